// Round 11
// baseline (176.444 us; speedup 1.0000x reference)
//
#include <hip/hip_runtime.h>
#include <hip/hip_bf16.h>
#include <math.h>

// ---------- helpers ----------
typedef short bf16x8 __attribute__((ext_vector_type(8)));
typedef float f32x4 __attribute__((ext_vector_type(4)));

__device__ __forceinline__ float bf2f(unsigned short u) {
    return __uint_as_float(((unsigned int)u) << 16);
}
__device__ __forceinline__ unsigned short f2bf(float f) {
    unsigned int u = __float_as_uint(f);
    u = (u + 0x7FFFu + ((u >> 16) & 1u)) >> 16;
    return (unsigned short)u;
}
__device__ __forceinline__ unsigned int pk2bf(float a, float b) {
    __hip_bfloat162 u = __float22bfloat162_rn(make_float2(a, b));
    return *(unsigned int*)&u;
}

// async global->LDS, 16B per lane; LDS dest = wave-uniform base + lane*16
#define ASYNC16(gp, lp)                                                        \
    __builtin_amdgcn_global_load_lds(                                          \
        (const __attribute__((address_space(1))) unsigned int*)(gp),           \
        (__attribute__((address_space(3))) unsigned int*)(lp), 16, 0, 0)

// ---------- prep: fp32 -> bf16 cast ----------
__global__ __launch_bounds__(256) void cast_x_kernel(const float* __restrict__ in,
                                                     unsigned short* __restrict__ out, int n) {
    int i = (blockIdx.x * 256 + threadIdx.x) * 8;
    if (i >= n) return;
    float4 a = *(const float4*)(in + i);
    float4 b = *(const float4*)(in + i + 4);
    bf16x8 v;
    v[0] = (short)f2bf(a.x); v[1] = (short)f2bf(a.y); v[2] = (short)f2bf(a.z); v[3] = (short)f2bf(a.w);
    v[4] = (short)f2bf(b.x); v[5] = (short)f2bf(b.y); v[6] = (short)f2bf(b.z); v[7] = (short)f2bf(b.w);
    *(bf16x8*)(out + i) = v;
}

// ---------- prep: fp32 [K][N] -> bf16 [N][K] (B^T layout for GEMM) ----------
__global__ __launch_bounds__(256) void transpose_cast_kernel(const float* __restrict__ in,
                                                             unsigned short* __restrict__ out,
                                                             int K, int N) {
    __shared__ float tile[32][33];
    int k0 = blockIdx.x * 32, n0 = blockIdx.y * 32;
    int tx = threadIdx.x & 31, ty = threadIdx.x >> 5;
    #pragma unroll
    for (int i = ty; i < 32; i += 8)
        tile[i][tx] = in[(size_t)(k0 + i) * N + (n0 + tx)];
    __syncthreads();
    #pragma unroll
    for (int i = ty; i < 32; i += 8)
        out[(size_t)(n0 + i) * K + (k0 + tx)] = f2bf(tile[tx][i]);
}

// ---------- prep: bf16 k-half of qkb [token][feature] -> kT [b*1024+f][token] ----------
__global__ __launch_bounds__(256) void ktrans_kernel(const unsigned short* __restrict__ qkb,
                                                     unsigned short* __restrict__ kT) {
    __shared__ unsigned short tl[64][68];
    const int b = blockIdx.z;
    const int tok0 = blockIdx.x * 64;
    const int f0 = blockIdx.y * 64;
    const int r = threadIdx.x >> 4;        // 0..15
    const int c = (threadIdx.x & 15) * 4;  // 0..60
    #pragma unroll
    for (int i = 0; i < 4; ++i) {
        const int rr = r + 16 * i;
        ushort4 v = *(const ushort4*)(qkb + ((size_t)(b * 2048 + tok0 + rr)) * 2048 + 1024 + f0 + c);
        *(ushort4*)&tl[rr][c] = v;
    }
    __syncthreads();
    #pragma unroll
    for (int i = 0; i < 4; ++i) {
        const int fr = r + 16 * i;
        ushort4 v;
        v.x = tl[c + 0][fr]; v.y = tl[c + 1][fr]; v.z = tl[c + 2][fr]; v.w = tl[c + 3][fr];
        *(ushort4*)(kT + ((size_t)(b * 1024 + f0 + fr)) * 2048 + tok0 + c) = v;
    }
}

// ---------- 64x128-tile, BK=64, DOUBLE-BUFFERED MFMA GEMM ----------
// v13 + the attn-proven pipeline: As/Bs double-buffered, prefetch next K-tile
// right after B1, counted s_waitcnt vmcnt(6) (own 6 DMAs landed, next 6 stay
// in flight), raw B2, compute. No in-loop vmcnt(0) drain -> per-iteration
// HBM/L2 latency hidden inside the block instead of only across blocks.
// LDS 48 KB -> 3 blocks/CU. XOR-swizzled staging/reads as v13 (conflict-free).
template <bool STORE_BF16>
__global__ __launch_bounds__(256) void gemm_db_kernel(const unsigned short* __restrict__ A,
                                                      const unsigned short* __restrict__ Bt,
                                                      void* __restrict__ C,
                                                      int K, int lda, int ldb, int ldc) {
    __shared__ unsigned short As[2][64 * 64];    // 2 x 8 KB
    __shared__ unsigned short Bs[2][128 * 64];   // 2 x 16 KB
    const int tid = threadIdx.x;
    const int wave = tid >> 6;
    const int lane = tid & 63;
    const int quad = lane >> 4;
    const int col  = lane & 15;
    const int sw   = col & 7;                 // read-side XOR key
    const int wm = (wave >> 1) * 32;          // 2 waves over M (64)
    const int wn = (wave & 1) * 64;           // 2 waves over N (128)
    const int m0 = blockIdx.x * 64, n0 = blockIdx.y * 128;

    f32x4 acc[2][4];
    #pragma unroll
    for (int i = 0; i < 2; ++i)
        #pragma unroll
        for (int j = 0; j < 4; ++j) { acc[i][j][0] = 0.f; acc[i][j][1] = 0.f; acc[i][j][2] = 0.f; acc[i][j][3] = 0.f; }

    // staging: wave covers rows wave*8 + r8 (+32/+64/+96), chunk c8 = (lane&7)^r8
    const int r8 = lane >> 3;
    const int c8 = (lane & 7) ^ r8;
    const unsigned short* gab = A  + (size_t)(m0 + wave * 8 + r8) * lda + c8 * 8;
    const unsigned short* gbb = Bt + (size_t)(n0 + wave * 8 + r8) * ldb + c8 * 8;

    auto issue = [&](int k0, int p) {
        const unsigned short* ga = gab + k0;
        const unsigned short* gb = gbb + k0;
        ASYNC16(ga,            &As[p][(wave * 8) * 64]);        // A rows 0..31
        ASYNC16(ga + 32 * lda, &As[p][(32 + wave * 8) * 64]);   // A rows 32..63
        ASYNC16(gb,            &Bs[p][(wave * 8) * 64]);        // B rows 0..31
        ASYNC16(gb + 32 * ldb, &Bs[p][(32 + wave * 8) * 64]);   // B rows 32..63
        ASYNC16(gb + 64 * ldb, &Bs[p][(64 + wave * 8) * 64]);   // B rows 64..95
        ASYNC16(gb + 96 * ldb, &Bs[p][(96 + wave * 8) * 64]);   // B rows 96..127
    };

    issue(0, 0);  // prologue: K-tile 0 -> buf 0

    const int nk = K >> 6;                    // K/64 tiles
    for (int kt = 0; kt < nk; ++kt) {
        const int cur = kt & 1;
        __builtin_amdgcn_s_barrier();         // B1: all waves done reading buf[cur^1]
        if (kt + 1 < nk) {
            issue((kt + 1) << 6, cur ^ 1);    // prefetch next K-tile (6 async, in flight)
            __builtin_amdgcn_s_waitcnt(0xF76);  // vmcnt(6): own tile-kt DMAs landed
        } else {
            __builtin_amdgcn_s_waitcnt(0xF70);  // vmcnt(0): last tile
        }
        __builtin_amdgcn_s_barrier();         // B2: everyone's tile-kt landed
        __asm__ volatile("" ::: "memory");    // fence compiler reordering across B2

        const unsigned short* Asc = &As[cur][0];
        const unsigned short* Bsc = &Bs[cur][0];

        bf16x8 af[2][2], bf[4][2];
        #pragma unroll
        for (int mf = 0; mf < 2; ++mf) {
            const int base = (wm + mf * 16 + col) * 64;
            af[mf][0] = *(const bf16x8*)&Asc[base + ((quad    ) ^ sw) * 8];
            af[mf][1] = *(const bf16x8*)&Asc[base + ((quad + 4) ^ sw) * 8];
        }
        #pragma unroll
        for (int nf = 0; nf < 4; ++nf) {
            const int base = (wn + nf * 16 + col) * 64;
            bf[nf][0] = *(const bf16x8*)&Bsc[base + ((quad    ) ^ sw) * 8];
            bf[nf][1] = *(const bf16x8*)&Bsc[base + ((quad + 4) ^ sw) * 8];
        }
        __builtin_amdgcn_s_setprio(1);
        #pragma unroll
        for (int mf = 0; mf < 2; ++mf)
            #pragma unroll
            for (int nf = 0; nf < 4; ++nf) {
                acc[mf][nf] = __builtin_amdgcn_mfma_f32_16x16x32_bf16(af[mf][0], bf[nf][0], acc[mf][nf], 0, 0, 0);
                acc[mf][nf] = __builtin_amdgcn_mfma_f32_16x16x32_bf16(af[mf][1], bf[nf][1], acc[mf][nf], 0, 0, 0);
            }
        __builtin_amdgcn_s_setprio(0);
    }

    #pragma unroll
    for (int mf = 0; mf < 2; ++mf) {
        const int row0 = m0 + wm + mf * 16 + quad * 4;
        #pragma unroll
        for (int nf = 0; nf < 4; ++nf) {
            const int cc = n0 + wn + nf * 16 + col;
            #pragma unroll
            for (int r = 0; r < 4; ++r) {
                if (STORE_BF16)
                    ((unsigned short*)C)[(size_t)(row0 + r) * ldc + cc] = f2bf(acc[mf][nf][r]);
                else
                    ((float*)C)[(size_t)(row0 + r) * ldc + cc] = acc[mf][nf][r];
            }
        }
    }
}

// ---------- MFMA flash attention v11: v9 + deferred-PV pipeline (frozen) ----------
__global__ __launch_bounds__(256, 4) void attn_v11_kernel(const unsigned short* __restrict__ qkb,
                                                          const unsigned short* __restrict__ kT,
                                                          unsigned short* __restrict__ aout) {
    __shared__ unsigned short Kbuf[2][2][64 * 64];  // [buf][Kn|Kt][key/dim][64], swizzled
    __shared__ unsigned short Ps[4][16 * 64];       // per-wave P: [query][key], XOR-swizzled

    const int bh = blockIdx.x;
    const int b = bh >> 4, h = bh & 15;
    const int qtile = 31 - (int)blockIdx.y;         // heavy tiles dispatch first
    const int tid = threadIdx.x;
    const int wave = tid >> 6, lane = tid & 63, quad = lane >> 4, col = lane & 15;
    const int sw = col & 7;                         // per-row XOR swizzle key

    // Q frags (B-operand of S^T mfma), fold beta*log2(e) so exp -> exp2
    bf16x8 qa0, qa1;
    {
        const unsigned short* qp =
            qkb + ((size_t)(b * 2048 + qtile * 64 + wave * 16 + col)) * 2048 + h * 64;
        bf16x8 r0 = *(const bf16x8*)(qp + quad * 8);
        bf16x8 r1 = *(const bf16x8*)(qp + 32 + quad * 8);
        const float sc = 0.125f * 1.44269504088896f;
        #pragma unroll
        for (int i = 0; i < 8; ++i) {
            qa0[i] = (short)f2bf(bf2f((unsigned short)r0[i]) * sc);
            qa1[i] = (short)f2bf(bf2f((unsigned short)r1[i]) * sc);
        }
    }

    bf16x8 ones;
    #pragma unroll
    for (int i = 0; i < 8; ++i) ones[i] = (short)0x3F80;  // bf16 1.0

    f32x4 accO[4];  // O[q=quad*4+r][d=t*16+col]
    #pragma unroll
    for (int t = 0; t < 4; ++t) { accO[t][0] = 0.f; accO[t][1] = 0.f; accO[t][2] = 0.f; accO[t][3] = 0.f; }
    f32x4 accL = {0.f, 0.f, 0.f, 0.f};  // row-sum of P (denominator), via ones-MFMA

    // carried fragments: P and V of the previous tile (deferred PV)
    bf16x8 pa0p = {}, pa1p = {};
    bf16x8 vlo[4] = {}, vhi[4] = {};

    // staging: lane covers row r8=lane/8 of an 8-row group, global chunk (lane%8)^r8
    const int r8 = lane >> 3;
    const int c8 = (lane & 7) ^ r8;
    const unsigned short* knp =
        qkb + ((size_t)(b * 2048 + wave * 16 + r8)) * 2048 + 1024 + h * 64 + c8 * 8;
    const unsigned short* ktp = kT + ((size_t)(bh * 64 + wave * 16 + r8)) * 2048 + c8 * 8;

    auto issue = [&](int jt, int p) {
        const unsigned short* kn = knp + (size_t)jt * 64 * 2048;
        const unsigned short* kt = ktp + jt * 64;
        unsigned short* knl = &Kbuf[p][0][(wave * 16) * 64];
        unsigned short* ktl = &Kbuf[p][1][(wave * 16) * 64];
        ASYNC16(kn,            knl);
        ASYNC16(kn + 8 * 2048, knl + 8 * 64);
        ASYNC16(kt,            ktl);
        ASYNC16(kt + 8 * 2048, ktl + 8 * 64);
    };

    issue(0, 0);  // prologue: tile 0 -> buf 0

    for (int jt = 0; jt <= qtile; ++jt) {
        const int cur = jt & 1;
        __builtin_amdgcn_s_barrier();            // B1: all waves done reading buf[cur^1]
        if (jt < qtile) issue(jt + 1, cur ^ 1);  // prefetch next tile (4 async, in flight)
        if (jt < qtile) __builtin_amdgcn_s_waitcnt(0xF74);  // vmcnt(4): own tile-jt landed
        else            __builtin_amdgcn_s_waitcnt(0xF70);  // vmcnt(0): last tile
        __builtin_amdgcn_s_barrier();            // B2: everyone's tile-jt landed
        __asm__ volatile("" ::: "memory");       // fence compiler reordering across B2

        const unsigned short* Knc = &Kbuf[cur][0][0];
        const unsigned short* Ktc = &Kbuf[cur][1][0];

        const bool diag = (jt == qtile);
        const int tmax = diag ? wave : 3;        // frag t = keys [t*16, t*16+15]

        // ---- QK MFMAs for tile jt, then deferred PV for tile jt-1 ----
        f32x4 c[4];
        __builtin_amdgcn_s_setprio(1);
        #pragma unroll
        for (int t = 0; t < 4; ++t) {
            if (t <= tmax) {
                const int row = (t * 16 + col) * 64;
                bf16x8 ka0 = *(const bf16x8*)&Knc[row + (quad ^ sw) * 8];
                bf16x8 ka1 = *(const bf16x8*)&Knc[row + ((4 + quad) ^ sw) * 8];
                f32x4 ci = {-16.f, -16.f, -16.f, -16.f};   // exp2 bias, free
                ci = __builtin_amdgcn_mfma_f32_16x16x32_bf16(ka0, qa0, ci, 0, 0, 0);
                ci = __builtin_amdgcn_mfma_f32_16x16x32_bf16(ka1, qa1, ci, 0, 0, 0);
                c[t] = ci;
            }
        }
        if (jt) {  // PV of tile jt-1 (always a full non-diag tile) on the MFMA pipe
            #pragma unroll
            for (int t = 0; t < 4; ++t) {
                accO[t] = __builtin_amdgcn_mfma_f32_16x16x32_bf16(pa0p, vlo[t], accO[t], 0, 0, 0);
                accO[t] = __builtin_amdgcn_mfma_f32_16x16x32_bf16(pa1p, vhi[t], accO[t], 0, 0, 0);
            }
            accL = __builtin_amdgcn_mfma_f32_16x16x32_bf16(pa0p, ones, accL, 0, 0, 0);
            accL = __builtin_amdgcn_mfma_f32_16x16x32_bf16(pa1p, ones, accL, 0, 0, 0);
        }
        __builtin_amdgcn_s_setprio(0);

        // ---- softmax (VALU) overlaps the PV MFMAs above ----
        unsigned int pw[4][2];
        #pragma unroll
        for (int t = 0; t < 4; ++t) {
            if (t <= tmax) {
                f32x4 ci = c[t];
                if (diag && t == wave) {
                    #pragma unroll
                    for (int r = 0; r < 4; ++r)
                        if (quad * 4 + r > col) ci[r] = -1e30f;   // exp2 -> 0
                }
                const float p0 = exp2f(ci[0]);
                const float p1 = exp2f(ci[1]);
                const float p2 = exp2f(ci[2]);
                const float p3 = exp2f(ci[3]);
                pw[t][0] = pk2bf(p0, p1);
                pw[t][1] = pk2bf(p2, p3);
            } else {
                pw[t][0] = 0u; pw[t][1] = 0u;
            }
        }

        // P -> LDS [query=col][key], XOR-swizzled 16B chunks (row = 128B = 8 chunks).
        unsigned short* psb = &Ps[wave][col * 64];
        #pragma unroll
        for (int t = 0; t < 4; ++t)
            *(uint2*)(psb + ((2 * t + (quad >> 1)) ^ sw) * 8 + (quad & 1) * 4) =
                make_uint2(pw[t][0], pw[t][1]);

        pa0p = *(const bf16x8*)(psb + (quad ^ sw) * 8);        // keys 0..31
        pa1p = *(const bf16x8*)(psb + ((4 + quad) ^ sw) * 8);  // keys 32..63

        // V frags of tile jt into registers (LDS read before next B1: contract kept)
        #pragma unroll
        for (int t = 0; t < 4; ++t) {
            const int row = (t * 16 + col) * 64;
            vlo[t] = *(const bf16x8*)&Ktc[row + (quad ^ sw) * 8];
            vhi[t] = *(const bf16x8*)&Ktc[row + ((4 + quad) ^ sw) * 8];
        }
    }

    // flush: PV of the last (diagonal) tile; masked keys carry P=0, so both
    // halves are safe unconditionally.
    #pragma unroll
    for (int t = 0; t < 4; ++t) {
        accO[t] = __builtin_amdgcn_mfma_f32_16x16x32_bf16(pa0p, vlo[t], accO[t], 0, 0, 0);
        accO[t] = __builtin_amdgcn_mfma_f32_16x16x32_bf16(pa1p, vhi[t], accO[t], 0, 0, 0);
    }
    accL = __builtin_amdgcn_mfma_f32_16x16x32_bf16(pa0p, ones, accL, 0, 0, 0);
    accL = __builtin_amdgcn_mfma_f32_16x16x32_bf16(pa1p, ones, accL, 0, 0, 0);

    // epilogue: accL[r] = denominator for query quad*4+r (replicated over cols)
    #pragma unroll
    for (int r = 0; r < 4; ++r) {
        const float inv = 1.f / accL[r];
        const size_t row = (size_t)b * 2048 + qtile * 64 + wave * 16 + quad * 4 + r;
        unsigned short* op = aout + row * 1024 + h * 64;
        op[col]      = f2bf(accO[0][r] * inv);
        op[16 + col] = f2bf(accO[1][r] * inv);
        op[32 + col] = f2bf(accO[2][r] * inv);
        op[48 + col] = f2bf(accO[3][r] * inv);
    }
}

// ---------- launch ----------
extern "C" void kernel_launch(void* const* d_in, const int* in_sizes, int n_in,
                              void* d_out, int out_size, void* d_ws, size_t ws_size,
                              hipStream_t stream) {
    (void)in_sizes; (void)n_in; (void)out_size; (void)ws_size;
    const float* x    = (const float*)d_in[0];   // [2,2048,1024]
    const float* Wqk  = (const float*)d_in[1];   // [1024,2048]
    const float* Wout = (const float*)d_in[2];   // [1024,1024]
    float* out = (float*)d_out;                  // [2,2048,1024] fp32

    unsigned short* xb     = (unsigned short*)d_ws;            // [4096][1024]
    unsigned short* Wqk_t  = xb     + (size_t)4096 * 1024;     // [2048][1024]
    unsigned short* Wout_t = Wqk_t  + (size_t)2048 * 1024;     // [1024][1024]
    unsigned short* qkb    = Wout_t + (size_t)1024 * 1024;     // [4096][2048]
    unsigned short* aoutb  = qkb    + (size_t)4096 * 2048;     // [4096][1024]
    unsigned short* kT     = xb;                               // [2048][2048] (x dead after GEMM1)

    cast_x_kernel<<<dim3(4096 * 1024 / (256 * 8)), dim3(256), 0, stream>>>(x, xb, 4096 * 1024);
    transpose_cast_kernel<<<dim3(32, 64), dim3(256), 0, stream>>>(Wqk, Wqk_t, 1024, 2048);
    transpose_cast_kernel<<<dim3(32, 32), dim3(256), 0, stream>>>(Wout, Wout_t, 1024, 1024);

    // qk = x @ W_qk -> bf16 [4096][2048]   (64x128, BK=64, double-buffered)
    gemm_db_kernel<true><<<dim3(64, 16), dim3(256), 0, stream>>>(
        xb, Wqk_t, (void*)qkb, 1024, 1024, 1024, 2048);

    // K^T per batch: [b*1024+f][token]
    ktrans_kernel<<<dim3(32, 16, 2), dim3(256), 0, stream>>>(qkb, kT);

    // causal MFMA flash attention (deferred-PV pipeline, 4 blocks/CU) -> bf16 [4096][1024]
    attn_v11_kernel<<<dim3(32, 32), dim3(256), 0, stream>>>(qkb, kT, aoutb);

    // out = attn_out @ W_out -> fp32       (64x128, BK=64, double-buffered)
    gemm_db_kernel<false><<<dim3(64, 8), dim3(256), 0, stream>>>(
        aoutb, Wout_t, (void*)out, 1024, 1024, 1024, 1024);
}

// Round 12
// 176.319 us; speedup vs baseline: 1.0007x; 1.0007x over previous
//
#include <hip/hip_runtime.h>
#include <hip/hip_bf16.h>
#include <math.h>

// ---------- helpers ----------
typedef short bf16x8 __attribute__((ext_vector_type(8)));
typedef float f32x4 __attribute__((ext_vector_type(4)));

__device__ __forceinline__ float bf2f(unsigned short u) {
    return __uint_as_float(((unsigned int)u) << 16);
}
__device__ __forceinline__ unsigned short f2bf(float f) {
    unsigned int u = __float_as_uint(f);
    u = (u + 0x7FFFu + ((u >> 16) & 1u)) >> 16;
    return (unsigned short)u;
}
__device__ __forceinline__ unsigned int pk2bf(float a, float b) {
    __hip_bfloat162 u = __float22bfloat162_rn(make_float2(a, b));
    return *(unsigned int*)&u;
}

// async global->LDS, 16B per lane; LDS dest = wave-uniform base + lane*16
#define ASYNC16(gp, lp)                                                        \
    __builtin_amdgcn_global_load_lds(                                          \
        (const __attribute__((address_space(1))) unsigned int*)(gp),           \
        (__attribute__((address_space(3))) unsigned int*)(lp), 16, 0, 0)

// ---------- fused prep: cast_x (blocks 0..2047), Wqk^T (2048..4095), Wout^T (4096..5119) ----------
// The three prep ops are independent; fusing them removes two kernel launches.
// Each block executes exactly one of the original kernel bodies (branch is
// block-uniform).
__global__ __launch_bounds__(256) void prep_kernel(const float* __restrict__ x,
                                                   const float* __restrict__ Wqk,
                                                   const float* __restrict__ Wout,
                                                   unsigned short* __restrict__ xb,
                                                   unsigned short* __restrict__ Wqk_t,
                                                   unsigned short* __restrict__ Wout_t) {
    __shared__ float tile[32][33];
    const int bid = blockIdx.x;
    const int tid = threadIdx.x;

    if (bid < 2048) {
        // ---- cast x: fp32 -> bf16, 8 elems/thread ----
        const int i = (bid * 256 + tid) * 8;
        float4 a = *(const float4*)(x + i);
        float4 b = *(const float4*)(x + i + 4);
        bf16x8 v;
        v[0] = (short)f2bf(a.x); v[1] = (short)f2bf(a.y); v[2] = (short)f2bf(a.z); v[3] = (short)f2bf(a.w);
        v[4] = (short)f2bf(b.x); v[5] = (short)f2bf(b.y); v[6] = (short)f2bf(b.z); v[7] = (short)f2bf(b.w);
        *(bf16x8*)(xb + i) = v;
        return;
    }

    // ---- transpose+cast: fp32 [K][N] -> bf16 [N][K] ----
    const float* in;
    unsigned short* out;
    int K, N, t;
    if (bid < 4096) { t = bid - 2048; in = Wqk;  out = Wqk_t;  K = 1024; N = 2048; }
    else            { t = bid - 4096; in = Wout; out = Wout_t; K = 1024; N = 1024; }
    const int k0 = (t & 31) * 32, n0 = (t >> 5) * 32;
    const int tx = tid & 31, ty = tid >> 5;
    #pragma unroll
    for (int i = ty; i < 32; i += 8)
        tile[i][tx] = in[(size_t)(k0 + i) * N + (n0 + tx)];
    __syncthreads();
    #pragma unroll
    for (int i = ty; i < 32; i += 8)
        out[(size_t)(n0 + i) * K + (k0 + tx)] = f2bf(tile[tx][i]);
}

// ---------- prep: bf16 k-half of qkb [token][feature] -> kT [b*1024+f][token] ----------
__global__ __launch_bounds__(256) void ktrans_kernel(const unsigned short* __restrict__ qkb,
                                                     unsigned short* __restrict__ kT) {
    __shared__ unsigned short tl[64][68];
    const int b = blockIdx.z;
    const int tok0 = blockIdx.x * 64;
    const int f0 = blockIdx.y * 64;
    const int r = threadIdx.x >> 4;        // 0..15
    const int c = (threadIdx.x & 15) * 4;  // 0..60
    #pragma unroll
    for (int i = 0; i < 4; ++i) {
        const int rr = r + 16 * i;
        ushort4 v = *(const ushort4*)(qkb + ((size_t)(b * 2048 + tok0 + rr)) * 2048 + 1024 + f0 + c);
        *(ushort4*)&tl[rr][c] = v;
    }
    __syncthreads();
    #pragma unroll
    for (int i = 0; i < 4; ++i) {
        const int fr = r + 16 * i;
        ushort4 v;
        v.x = tl[c + 0][fr]; v.y = tl[c + 1][fr]; v.z = tl[c + 2][fr]; v.w = tl[c + 3][fr];
        *(ushort4*)(kT + ((size_t)(b * 1024 + f0 + fr)) * 2048 + tok0 + c) = v;
    }
}

// ---------- 64x128-tile, BK=64 MFMA GEMM (v13, reverted: stable numerics) ----------
// 2-barrier K-loop with full __syncthreads (drains vmcnt+lgkm: no ordering
// hazards). XOR-swizzled staging via pre-swizzled global source, conflict-free
// reads. LDS 24.5KB -> 4 blocks/CU (gemm1).
template <bool STORE_BF16>
__global__ __launch_bounds__(256) void gemm64k_kernel(const unsigned short* __restrict__ A,
                                                      const unsigned short* __restrict__ Bt,
                                                      void* __restrict__ C,
                                                      int K, int lda, int ldb, int ldc) {
    __shared__ unsigned short As[64 * 64];    // 8 KB
    __shared__ unsigned short Bs[128 * 64];   // 16 KB
    const int tid = threadIdx.x;
    const int wave = tid >> 6;
    const int lane = tid & 63;
    const int quad = lane >> 4;
    const int col  = lane & 15;
    const int sw   = col & 7;                 // read-side XOR key
    const int wm = (wave >> 1) * 32;          // 2 waves over M (64)
    const int wn = (wave & 1) * 64;           // 2 waves over N (128)
    const int m0 = blockIdx.x * 64, n0 = blockIdx.y * 128;

    f32x4 acc[2][4];
    #pragma unroll
    for (int i = 0; i < 2; ++i)
        #pragma unroll
        for (int j = 0; j < 4; ++j) { acc[i][j][0] = 0.f; acc[i][j][1] = 0.f; acc[i][j][2] = 0.f; acc[i][j][3] = 0.f; }

    // staging: wave covers rows wave*8 + r8 (+32/+64/+96), chunk c8 = (lane&7)^r8
    const int r8 = lane >> 3;
    const int c8 = (lane & 7) ^ r8;

    for (int k0 = 0; k0 < K; k0 += 64) {
        __syncthreads();
        const unsigned short* ga = A  + (size_t)(m0 + wave * 8 + r8) * lda + k0 + c8 * 8;
        const unsigned short* gb = Bt + (size_t)(n0 + wave * 8 + r8) * ldb + k0 + c8 * 8;
        ASYNC16(ga,            &As[(wave * 8) * 64]);        // A rows 0..31
        ASYNC16(ga + 32 * lda, &As[(32 + wave * 8) * 64]);   // A rows 32..63
        ASYNC16(gb,            &Bs[(wave * 8) * 64]);        // B rows 0..31
        ASYNC16(gb + 32 * ldb, &Bs[(32 + wave * 8) * 64]);   // B rows 32..63
        ASYNC16(gb + 64 * ldb, &Bs[(64 + wave * 8) * 64]);   // B rows 64..95
        ASYNC16(gb + 96 * ldb, &Bs[(96 + wave * 8) * 64]);   // B rows 96..127
        __syncthreads();

        bf16x8 af[2][2], bf[4][2];
        #pragma unroll
        for (int mf = 0; mf < 2; ++mf) {
            const int base = (wm + mf * 16 + col) * 64;
            af[mf][0] = *(const bf16x8*)&As[base + ((quad    ) ^ sw) * 8];
            af[mf][1] = *(const bf16x8*)&As[base + ((quad + 4) ^ sw) * 8];
        }
        #pragma unroll
        for (int nf = 0; nf < 4; ++nf) {
            const int base = (wn + nf * 16 + col) * 64;
            bf[nf][0] = *(const bf16x8*)&Bs[base + ((quad    ) ^ sw) * 8];
            bf[nf][1] = *(const bf16x8*)&Bs[base + ((quad + 4) ^ sw) * 8];
        }
        #pragma unroll
        for (int mf = 0; mf < 2; ++mf)
            #pragma unroll
            for (int nf = 0; nf < 4; ++nf) {
                acc[mf][nf] = __builtin_amdgcn_mfma_f32_16x16x32_bf16(af[mf][0], bf[nf][0], acc[mf][nf], 0, 0, 0);
                acc[mf][nf] = __builtin_amdgcn_mfma_f32_16x16x32_bf16(af[mf][1], bf[nf][1], acc[mf][nf], 0, 0, 0);
            }
    }

    #pragma unroll
    for (int mf = 0; mf < 2; ++mf) {
        const int row0 = m0 + wm + mf * 16 + quad * 4;
        #pragma unroll
        for (int nf = 0; nf < 4; ++nf) {
            const int cc = n0 + wn + nf * 16 + col;
            #pragma unroll
            for (int r = 0; r < 4; ++r) {
                if (STORE_BF16)
                    ((unsigned short*)C)[(size_t)(row0 + r) * ldc + cc] = f2bf(acc[mf][nf][r]);
                else
                    ((float*)C)[(size_t)(row0 + r) * ldc + cc] = acc[mf][nf][r];
            }
        }
    }
}

// ---------- MFMA flash attention v11: v9 + deferred-PV pipeline (frozen) ----------
__global__ __launch_bounds__(256, 4) void attn_v11_kernel(const unsigned short* __restrict__ qkb,
                                                          const unsigned short* __restrict__ kT,
                                                          unsigned short* __restrict__ aout) {
    __shared__ unsigned short Kbuf[2][2][64 * 64];  // [buf][Kn|Kt][key/dim][64], swizzled
    __shared__ unsigned short Ps[4][16 * 64];       // per-wave P: [query][key], XOR-swizzled

    const int bh = blockIdx.x;
    const int b = bh >> 4, h = bh & 15;
    const int qtile = 31 - (int)blockIdx.y;         // heavy tiles dispatch first
    const int tid = threadIdx.x;
    const int wave = tid >> 6, lane = tid & 63, quad = lane >> 4, col = lane & 15;
    const int sw = col & 7;                         // per-row XOR swizzle key

    // Q frags (B-operand of S^T mfma), fold beta*log2(e) so exp -> exp2
    bf16x8 qa0, qa1;
    {
        const unsigned short* qp =
            qkb + ((size_t)(b * 2048 + qtile * 64 + wave * 16 + col)) * 2048 + h * 64;
        bf16x8 r0 = *(const bf16x8*)(qp + quad * 8);
        bf16x8 r1 = *(const bf16x8*)(qp + 32 + quad * 8);
        const float sc = 0.125f * 1.44269504088896f;
        #pragma unroll
        for (int i = 0; i < 8; ++i) {
            qa0[i] = (short)f2bf(bf2f((unsigned short)r0[i]) * sc);
            qa1[i] = (short)f2bf(bf2f((unsigned short)r1[i]) * sc);
        }
    }

    bf16x8 ones;
    #pragma unroll
    for (int i = 0; i < 8; ++i) ones[i] = (short)0x3F80;  // bf16 1.0

    f32x4 accO[4];  // O[q=quad*4+r][d=t*16+col]
    #pragma unroll
    for (int t = 0; t < 4; ++t) { accO[t][0] = 0.f; accO[t][1] = 0.f; accO[t][2] = 0.f; accO[t][3] = 0.f; }
    f32x4 accL = {0.f, 0.f, 0.f, 0.f};  // row-sum of P (denominator), via ones-MFMA

    // carried fragments: P and V of the previous tile (deferred PV)
    bf16x8 pa0p = {}, pa1p = {};
    bf16x8 vlo[4] = {}, vhi[4] = {};

    // staging: lane covers row r8=lane/8 of an 8-row group, global chunk (lane%8)^r8
    const int r8 = lane >> 3;
    const int c8 = (lane & 7) ^ r8;
    const unsigned short* knp =
        qkb + ((size_t)(b * 2048 + wave * 16 + r8)) * 2048 + 1024 + h * 64 + c8 * 8;
    const unsigned short* ktp = kT + ((size_t)(bh * 64 + wave * 16 + r8)) * 2048 + c8 * 8;

    auto issue = [&](int jt, int p) {
        const unsigned short* kn = knp + (size_t)jt * 64 * 2048;
        const unsigned short* kt = ktp + jt * 64;
        unsigned short* knl = &Kbuf[p][0][(wave * 16) * 64];
        unsigned short* ktl = &Kbuf[p][1][(wave * 16) * 64];
        ASYNC16(kn,            knl);
        ASYNC16(kn + 8 * 2048, knl + 8 * 64);
        ASYNC16(kt,            ktl);
        ASYNC16(kt + 8 * 2048, ktl + 8 * 64);
    };

    issue(0, 0);  // prologue: tile 0 -> buf 0

    for (int jt = 0; jt <= qtile; ++jt) {
        const int cur = jt & 1;
        __builtin_amdgcn_s_barrier();            // B1: all waves done reading buf[cur^1]
        if (jt < qtile) issue(jt + 1, cur ^ 1);  // prefetch next tile (4 async, in flight)
        if (jt < qtile) __builtin_amdgcn_s_waitcnt(0xF74);  // vmcnt(4): own tile-jt landed
        else            __builtin_amdgcn_s_waitcnt(0xF70);  // vmcnt(0): last tile
        __builtin_amdgcn_s_barrier();            // B2: everyone's tile-jt landed
        __asm__ volatile("" ::: "memory");       // fence compiler reordering across B2

        const unsigned short* Knc = &Kbuf[cur][0][0];
        const unsigned short* Ktc = &Kbuf[cur][1][0];

        const bool diag = (jt == qtile);
        const int tmax = diag ? wave : 3;        // frag t = keys [t*16, t*16+15]

        // ---- QK MFMAs for tile jt, then deferred PV for tile jt-1 ----
        f32x4 c[4];
        __builtin_amdgcn_s_setprio(1);
        #pragma unroll
        for (int t = 0; t < 4; ++t) {
            if (t <= tmax) {
                const int row = (t * 16 + col) * 64;
                bf16x8 ka0 = *(const bf16x8*)&Knc[row + (quad ^ sw) * 8];
                bf16x8 ka1 = *(const bf16x8*)&Knc[row + ((4 + quad) ^ sw) * 8];
                f32x4 ci = {-16.f, -16.f, -16.f, -16.f};   // exp2 bias, free
                ci = __builtin_amdgcn_mfma_f32_16x16x32_bf16(ka0, qa0, ci, 0, 0, 0);
                ci = __builtin_amdgcn_mfma_f32_16x16x32_bf16(ka1, qa1, ci, 0, 0, 0);
                c[t] = ci;
            }
        }
        if (jt) {  // PV of tile jt-1 (always a full non-diag tile) on the MFMA pipe
            #pragma unroll
            for (int t = 0; t < 4; ++t) {
                accO[t] = __builtin_amdgcn_mfma_f32_16x16x32_bf16(pa0p, vlo[t], accO[t], 0, 0, 0);
                accO[t] = __builtin_amdgcn_mfma_f32_16x16x32_bf16(pa1p, vhi[t], accO[t], 0, 0, 0);
            }
            accL = __builtin_amdgcn_mfma_f32_16x16x32_bf16(pa0p, ones, accL, 0, 0, 0);
            accL = __builtin_amdgcn_mfma_f32_16x16x32_bf16(pa1p, ones, accL, 0, 0, 0);
        }
        __builtin_amdgcn_s_setprio(0);

        // ---- softmax (VALU) overlaps the PV MFMAs above ----
        unsigned int pw[4][2];
        #pragma unroll
        for (int t = 0; t < 4; ++t) {
            if (t <= tmax) {
                f32x4 ci = c[t];
                if (diag && t == wave) {
                    #pragma unroll
                    for (int r = 0; r < 4; ++r)
                        if (quad * 4 + r > col) ci[r] = -1e30f;   // exp2 -> 0
                }
                const float p0 = exp2f(ci[0]);
                const float p1 = exp2f(ci[1]);
                const float p2 = exp2f(ci[2]);
                const float p3 = exp2f(ci[3]);
                pw[t][0] = pk2bf(p0, p1);
                pw[t][1] = pk2bf(p2, p3);
            } else {
                pw[t][0] = 0u; pw[t][1] = 0u;
            }
        }

        // P -> LDS [query=col][key], XOR-swizzled 16B chunks (row = 128B = 8 chunks).
        unsigned short* psb = &Ps[wave][col * 64];
        #pragma unroll
        for (int t = 0; t < 4; ++t)
            *(uint2*)(psb + ((2 * t + (quad >> 1)) ^ sw) * 8 + (quad & 1) * 4) =
                make_uint2(pw[t][0], pw[t][1]);

        pa0p = *(const bf16x8*)(psb + (quad ^ sw) * 8);        // keys 0..31
        pa1p = *(const bf16x8*)(psb + ((4 + quad) ^ sw) * 8);  // keys 32..63

        // V frags of tile jt into registers (LDS read before next B1: contract kept)
        #pragma unroll
        for (int t = 0; t < 4; ++t) {
            const int row = (t * 16 + col) * 64;
            vlo[t] = *(const bf16x8*)&Ktc[row + (quad ^ sw) * 8];
            vhi[t] = *(const bf16x8*)&Ktc[row + ((4 + quad) ^ sw) * 8];
        }
    }

    // flush: PV of the last (diagonal) tile; masked keys carry P=0, so both
    // halves are safe unconditionally.
    #pragma unroll
    for (int t = 0; t < 4; ++t) {
        accO[t] = __builtin_amdgcn_mfma_f32_16x16x32_bf16(pa0p, vlo[t], accO[t], 0, 0, 0);
        accO[t] = __builtin_amdgcn_mfma_f32_16x16x32_bf16(pa1p, vhi[t], accO[t], 0, 0, 0);
    }
    accL = __builtin_amdgcn_mfma_f32_16x16x32_bf16(pa0p, ones, accL, 0, 0, 0);
    accL = __builtin_amdgcn_mfma_f32_16x16x32_bf16(pa1p, ones, accL, 0, 0, 0);

    // epilogue: accL[r] = denominator for query quad*4+r (replicated over cols)
    #pragma unroll
    for (int r = 0; r < 4; ++r) {
        const float inv = 1.f / accL[r];
        const size_t row = (size_t)b * 2048 + qtile * 64 + wave * 16 + quad * 4 + r;
        unsigned short* op = aout + row * 1024 + h * 64;
        op[col]      = f2bf(accO[0][r] * inv);
        op[16 + col] = f2bf(accO[1][r] * inv);
        op[32 + col] = f2bf(accO[2][r] * inv);
        op[48 + col] = f2bf(accO[3][r] * inv);
    }
}

// ---------- launch ----------
extern "C" void kernel_launch(void* const* d_in, const int* in_sizes, int n_in,
                              void* d_out, int out_size, void* d_ws, size_t ws_size,
                              hipStream_t stream) {
    (void)in_sizes; (void)n_in; (void)out_size; (void)ws_size;
    const float* x    = (const float*)d_in[0];   // [2,2048,1024]
    const float* Wqk  = (const float*)d_in[1];   // [1024,2048]
    const float* Wout = (const float*)d_in[2];   // [1024,1024]
    float* out = (float*)d_out;                  // [2,2048,1024] fp32

    unsigned short* xb     = (unsigned short*)d_ws;            // [4096][1024]
    unsigned short* Wqk_t  = xb     + (size_t)4096 * 1024;     // [2048][1024]
    unsigned short* Wout_t = Wqk_t  + (size_t)2048 * 1024;     // [1024][1024]
    unsigned short* qkb    = Wout_t + (size_t)1024 * 1024;     // [4096][2048]
    unsigned short* aoutb  = qkb    + (size_t)4096 * 2048;     // [4096][1024]
    unsigned short* kT     = xb;                               // [2048][2048] (x dead after GEMM1)

    // fused prep: cast_x + Wqk^T + Wout^T in one dispatch
    prep_kernel<<<dim3(5120), dim3(256), 0, stream>>>(x, Wqk, Wout, xb, Wqk_t, Wout_t);

    // qk = x @ W_qk -> bf16 [4096][2048]   (64x128 tiles, BK=64: 1024 blocks = 4/CU)
    gemm64k_kernel<true><<<dim3(64, 16), dim3(256), 0, stream>>>(
        xb, Wqk_t, (void*)qkb, 1024, 1024, 1024, 2048);

    // K^T per batch: [b*1024+f][token]
    ktrans_kernel<<<dim3(32, 16, 2), dim3(256), 0, stream>>>(qkb, kT);

    // causal MFMA flash attention (deferred-PV pipeline, 4 blocks/CU) -> bf16 [4096][1024]
    attn_v11_kernel<<<dim3(32, 32), dim3(256), 0, stream>>>(qkb, kT, aoutb);

    // out = attn_out @ W_out -> fp32       (64x128 tiles, BK=64: 512 blocks = 2/CU)
    gemm64k_kernel<false><<<dim3(64, 8), dim3(256), 0, stream>>>(
        aoutb, Wout_t, (void*)out, 1024, 1024, 1024, 1024);
}

// Round 13
// 167.054 us; speedup vs baseline: 1.0562x; 1.0555x over previous
//
#include <hip/hip_runtime.h>
#include <hip/hip_bf16.h>
#include <math.h>

// ---------- helpers ----------
typedef short bf16x8 __attribute__((ext_vector_type(8)));
typedef float f32x4 __attribute__((ext_vector_type(4)));

__device__ __forceinline__ float bf2f(unsigned short u) {
    return __uint_as_float(((unsigned int)u) << 16);
}
__device__ __forceinline__ unsigned short f2bf(float f) {
    unsigned int u = __float_as_uint(f);
    u = (u + 0x7FFFu + ((u >> 16) & 1u)) >> 16;
    return (unsigned short)u;
}
__device__ __forceinline__ unsigned int pk2bf(float a, float b) {
    __hip_bfloat162 u = __float22bfloat162_rn(make_float2(a, b));
    return *(unsigned int*)&u;
}

// async global->LDS, 16B per lane; LDS dest = wave-uniform base + lane*16
#define ASYNC16(gp, lp)                                                        \
    __builtin_amdgcn_global_load_lds(                                          \
        (const __attribute__((address_space(1))) unsigned int*)(gp),           \
        (__attribute__((address_space(3))) unsigned int*)(lp), 16, 0, 0)

// ---------- fused prep: cast_x (blocks 0..2047), Wqk^T (2048..4095), Wout^T (4096..5119) ----------
__global__ __launch_bounds__(256) void prep_kernel(const float* __restrict__ x,
                                                   const float* __restrict__ Wqk,
                                                   const float* __restrict__ Wout,
                                                   unsigned short* __restrict__ xb,
                                                   unsigned short* __restrict__ Wqk_t,
                                                   unsigned short* __restrict__ Wout_t) {
    __shared__ float tile[32][33];
    const int bid = blockIdx.x;
    const int tid = threadIdx.x;

    if (bid < 2048) {
        // ---- cast x: fp32 -> bf16, 8 elems/thread ----
        const int i = (bid * 256 + tid) * 8;
        float4 a = *(const float4*)(x + i);
        float4 b = *(const float4*)(x + i + 4);
        bf16x8 v;
        v[0] = (short)f2bf(a.x); v[1] = (short)f2bf(a.y); v[2] = (short)f2bf(a.z); v[3] = (short)f2bf(a.w);
        v[4] = (short)f2bf(b.x); v[5] = (short)f2bf(b.y); v[6] = (short)f2bf(b.z); v[7] = (short)f2bf(b.w);
        *(bf16x8*)(xb + i) = v;
        return;
    }

    // ---- transpose+cast: fp32 [K][N] -> bf16 [N][K] ----
    const float* in;
    unsigned short* out;
    int K, N, t;
    if (bid < 4096) { t = bid - 2048; in = Wqk;  out = Wqk_t;  K = 1024; N = 2048; }
    else            { t = bid - 4096; in = Wout; out = Wout_t; K = 1024; N = 1024; }
    const int k0 = (t & 31) * 32, n0 = (t >> 5) * 32;
    const int tx = tid & 31, ty = tid >> 5;
    #pragma unroll
    for (int i = ty; i < 32; i += 8)
        tile[i][tx] = in[(size_t)(k0 + i) * N + (n0 + tx)];
    __syncthreads();
    #pragma unroll
    for (int i = ty; i < 32; i += 8)
        out[(size_t)(n0 + i) * K + (k0 + tx)] = f2bf(tile[tx][i]);
}

// ---------- prep: bf16 k-half of qkb [token][feature] -> kT [b*1024+f][token] ----------
__global__ __launch_bounds__(256) void ktrans_kernel(const unsigned short* __restrict__ qkb,
                                                     unsigned short* __restrict__ kT) {
    __shared__ unsigned short tl[64][68];
    const int b = blockIdx.z;
    const int tok0 = blockIdx.x * 64;
    const int f0 = blockIdx.y * 64;
    const int r = threadIdx.x >> 4;        // 0..15
    const int c = (threadIdx.x & 15) * 4;  // 0..60
    #pragma unroll
    for (int i = 0; i < 4; ++i) {
        const int rr = r + 16 * i;
        ushort4 v = *(const ushort4*)(qkb + ((size_t)(b * 2048 + tok0 + rr)) * 2048 + 1024 + f0 + c);
        *(ushort4*)&tl[rr][c] = v;
    }
    __syncthreads();
    #pragma unroll
    for (int i = 0; i < 4; ++i) {
        const int fr = r + 16 * i;
        ushort4 v;
        v.x = tl[c + 0][fr]; v.y = tl[c + 1][fr]; v.z = tl[c + 2][fr]; v.w = tl[c + 3][fr];
        *(ushort4*)(kT + ((size_t)(b * 1024 + f0 + fr)) * 2048 + tok0 + c) = v;
    }
}

// ---------- 64x128-tile, BK=64 MFMA GEMM (v13: stable, full-drain barriers) ----------
template <bool STORE_BF16>
__global__ __launch_bounds__(256) void gemm64k_kernel(const unsigned short* __restrict__ A,
                                                      const unsigned short* __restrict__ Bt,
                                                      void* __restrict__ C,
                                                      int K, int lda, int ldb, int ldc) {
    __shared__ unsigned short As[64 * 64];    // 8 KB
    __shared__ unsigned short Bs[128 * 64];   // 16 KB
    const int tid = threadIdx.x;
    const int wave = tid >> 6;
    const int lane = tid & 63;
    const int quad = lane >> 4;
    const int col  = lane & 15;
    const int sw   = col & 7;                 // read-side XOR key
    const int wm = (wave >> 1) * 32;          // 2 waves over M (64)
    const int wn = (wave & 1) * 64;           // 2 waves over N (128)
    const int m0 = blockIdx.x * 64, n0 = blockIdx.y * 128;

    f32x4 acc[2][4];
    #pragma unroll
    for (int i = 0; i < 2; ++i)
        #pragma unroll
        for (int j = 0; j < 4; ++j) { acc[i][j][0] = 0.f; acc[i][j][1] = 0.f; acc[i][j][2] = 0.f; acc[i][j][3] = 0.f; }

    // staging: wave covers rows wave*8 + r8 (+32/+64/+96), chunk c8 = (lane&7)^r8
    const int r8 = lane >> 3;
    const int c8 = (lane & 7) ^ r8;

    for (int k0 = 0; k0 < K; k0 += 64) {
        __syncthreads();
        const unsigned short* ga = A  + (size_t)(m0 + wave * 8 + r8) * lda + k0 + c8 * 8;
        const unsigned short* gb = Bt + (size_t)(n0 + wave * 8 + r8) * ldb + k0 + c8 * 8;
        ASYNC16(ga,            &As[(wave * 8) * 64]);        // A rows 0..31
        ASYNC16(ga + 32 * lda, &As[(32 + wave * 8) * 64]);   // A rows 32..63
        ASYNC16(gb,            &Bs[(wave * 8) * 64]);        // B rows 0..31
        ASYNC16(gb + 32 * ldb, &Bs[(32 + wave * 8) * 64]);   // B rows 32..63
        ASYNC16(gb + 64 * ldb, &Bs[(64 + wave * 8) * 64]);   // B rows 64..95
        ASYNC16(gb + 96 * ldb, &Bs[(96 + wave * 8) * 64]);   // B rows 96..127
        __syncthreads();

        bf16x8 af[2][2], bf[4][2];
        #pragma unroll
        for (int mf = 0; mf < 2; ++mf) {
            const int base = (wm + mf * 16 + col) * 64;
            af[mf][0] = *(const bf16x8*)&As[base + ((quad    ) ^ sw) * 8];
            af[mf][1] = *(const bf16x8*)&As[base + ((quad + 4) ^ sw) * 8];
        }
        #pragma unroll
        for (int nf = 0; nf < 4; ++nf) {
            const int base = (wn + nf * 16 + col) * 64;
            bf[nf][0] = *(const bf16x8*)&Bs[base + ((quad    ) ^ sw) * 8];
            bf[nf][1] = *(const bf16x8*)&Bs[base + ((quad + 4) ^ sw) * 8];
        }
        #pragma unroll
        for (int mf = 0; mf < 2; ++mf)
            #pragma unroll
            for (int nf = 0; nf < 4; ++nf) {
                acc[mf][nf] = __builtin_amdgcn_mfma_f32_16x16x32_bf16(af[mf][0], bf[nf][0], acc[mf][nf], 0, 0, 0);
                acc[mf][nf] = __builtin_amdgcn_mfma_f32_16x16x32_bf16(af[mf][1], bf[nf][1], acc[mf][nf], 0, 0, 0);
            }
    }

    #pragma unroll
    for (int mf = 0; mf < 2; ++mf) {
        const int row0 = m0 + wm + mf * 16 + quad * 4;
        #pragma unroll
        for (int nf = 0; nf < 4; ++nf) {
            const int cc = n0 + wn + nf * 16 + col;
            #pragma unroll
            for (int r = 0; r < 4; ++r) {
                if (STORE_BF16)
                    ((unsigned short*)C)[(size_t)(row0 + r) * ldc + cc] = f2bf(acc[mf][nf][r]);
                else
                    ((float*)C)[(size_t)(row0 + r) * ldc + cc] = acc[mf][nf][r];
            }
        }
    }
}

// ---------- MFMA flash attention v16: v11 + race fix ----------
// v11's deferred-PV left the V-frag ds_reads (cross-wave Kbuf rows) possibly
// outstanding across B1; after B1 other waves' global_load_lds DMAs overwrite
// those rows -> timing-dependent corruption (observed as run-to-run absmax
// drift 0.0078->0.0222->0.009 on identical source). Fix: drain lgkmcnt(0)
// (+ sched_barrier to pin the loads) BEFORE looping back to B1. vmcnt is
// untouched: prefetch DMAs stay in flight.
__global__ __launch_bounds__(256, 4) void attn_v16_kernel(const unsigned short* __restrict__ qkb,
                                                          const unsigned short* __restrict__ kT,
                                                          unsigned short* __restrict__ aout) {
    __shared__ unsigned short Kbuf[2][2][64 * 64];  // [buf][Kn|Kt][key/dim][64], swizzled
    __shared__ unsigned short Ps[4][16 * 64];       // per-wave P: [query][key], XOR-swizzled

    const int bh = blockIdx.x;
    const int b = bh >> 4, h = bh & 15;
    const int qtile = 31 - (int)blockIdx.y;         // heavy tiles dispatch first
    const int tid = threadIdx.x;
    const int wave = tid >> 6, lane = tid & 63, quad = lane >> 4, col = lane & 15;
    const int sw = col & 7;                         // per-row XOR swizzle key

    // Q frags (B-operand of S^T mfma), fold beta*log2(e) so exp -> exp2
    bf16x8 qa0, qa1;
    {
        const unsigned short* qp =
            qkb + ((size_t)(b * 2048 + qtile * 64 + wave * 16 + col)) * 2048 + h * 64;
        bf16x8 r0 = *(const bf16x8*)(qp + quad * 8);
        bf16x8 r1 = *(const bf16x8*)(qp + 32 + quad * 8);
        const float sc = 0.125f * 1.44269504088896f;
        #pragma unroll
        for (int i = 0; i < 8; ++i) {
            qa0[i] = (short)f2bf(bf2f((unsigned short)r0[i]) * sc);
            qa1[i] = (short)f2bf(bf2f((unsigned short)r1[i]) * sc);
        }
    }

    bf16x8 ones;
    #pragma unroll
    for (int i = 0; i < 8; ++i) ones[i] = (short)0x3F80;  // bf16 1.0

    f32x4 accO[4];  // O[q=quad*4+r][d=t*16+col]
    #pragma unroll
    for (int t = 0; t < 4; ++t) { accO[t][0] = 0.f; accO[t][1] = 0.f; accO[t][2] = 0.f; accO[t][3] = 0.f; }
    f32x4 accL = {0.f, 0.f, 0.f, 0.f};  // row-sum of P (denominator), via ones-MFMA

    // carried fragments: P and V of the previous tile (deferred PV)
    bf16x8 pa0p = {}, pa1p = {};
    bf16x8 vlo[4] = {}, vhi[4] = {};

    // staging: lane covers row r8=lane/8 of an 8-row group, global chunk (lane%8)^r8
    const int r8 = lane >> 3;
    const int c8 = (lane & 7) ^ r8;
    const unsigned short* knp =
        qkb + ((size_t)(b * 2048 + wave * 16 + r8)) * 2048 + 1024 + h * 64 + c8 * 8;
    const unsigned short* ktp = kT + ((size_t)(bh * 64 + wave * 16 + r8)) * 2048 + c8 * 8;

    auto issue = [&](int jt, int p) {
        const unsigned short* kn = knp + (size_t)jt * 64 * 2048;
        const unsigned short* kt = ktp + jt * 64;
        unsigned short* knl = &Kbuf[p][0][(wave * 16) * 64];
        unsigned short* ktl = &Kbuf[p][1][(wave * 16) * 64];
        ASYNC16(kn,            knl);
        ASYNC16(kn + 8 * 2048, knl + 8 * 64);
        ASYNC16(kt,            ktl);
        ASYNC16(kt + 8 * 2048, ktl + 8 * 64);
    };

    issue(0, 0);  // prologue: tile 0 -> buf 0

    for (int jt = 0; jt <= qtile; ++jt) {
        const int cur = jt & 1;
        __builtin_amdgcn_s_barrier();            // B1: all waves done reading buf[cur^1]
        if (jt < qtile) issue(jt + 1, cur ^ 1);  // prefetch next tile (4 async, in flight)
        if (jt < qtile) __builtin_amdgcn_s_waitcnt(0xF74);  // vmcnt(4): own tile-jt landed
        else            __builtin_amdgcn_s_waitcnt(0xF70);  // vmcnt(0): last tile
        __builtin_amdgcn_s_barrier();            // B2: everyone's tile-jt landed
        __asm__ volatile("" ::: "memory");       // fence compiler reordering across B2

        const unsigned short* Knc = &Kbuf[cur][0][0];
        const unsigned short* Ktc = &Kbuf[cur][1][0];

        const bool diag = (jt == qtile);
        const int tmax = diag ? wave : 3;        // frag t = keys [t*16, t*16+15]

        // ---- QK MFMAs for tile jt, then deferred PV for tile jt-1 ----
        f32x4 c[4];
        __builtin_amdgcn_s_setprio(1);
        #pragma unroll
        for (int t = 0; t < 4; ++t) {
            if (t <= tmax) {
                const int row = (t * 16 + col) * 64;
                bf16x8 ka0 = *(const bf16x8*)&Knc[row + (quad ^ sw) * 8];
                bf16x8 ka1 = *(const bf16x8*)&Knc[row + ((4 + quad) ^ sw) * 8];
                f32x4 ci = {-16.f, -16.f, -16.f, -16.f};   // exp2 bias, free
                ci = __builtin_amdgcn_mfma_f32_16x16x32_bf16(ka0, qa0, ci, 0, 0, 0);
                ci = __builtin_amdgcn_mfma_f32_16x16x32_bf16(ka1, qa1, ci, 0, 0, 0);
                c[t] = ci;
            }
        }
        if (jt) {  // PV of tile jt-1 (always a full non-diag tile) on the MFMA pipe
            #pragma unroll
            for (int t = 0; t < 4; ++t) {
                accO[t] = __builtin_amdgcn_mfma_f32_16x16x32_bf16(pa0p, vlo[t], accO[t], 0, 0, 0);
                accO[t] = __builtin_amdgcn_mfma_f32_16x16x32_bf16(pa1p, vhi[t], accO[t], 0, 0, 0);
            }
            accL = __builtin_amdgcn_mfma_f32_16x16x32_bf16(pa0p, ones, accL, 0, 0, 0);
            accL = __builtin_amdgcn_mfma_f32_16x16x32_bf16(pa1p, ones, accL, 0, 0, 0);
        }
        __builtin_amdgcn_s_setprio(0);

        // ---- softmax (VALU) overlaps the PV MFMAs above ----
        unsigned int pw[4][2];
        #pragma unroll
        for (int t = 0; t < 4; ++t) {
            if (t <= tmax) {
                f32x4 ci = c[t];
                if (diag && t == wave) {
                    #pragma unroll
                    for (int r = 0; r < 4; ++r)
                        if (quad * 4 + r > col) ci[r] = -1e30f;   // exp2 -> 0
                }
                const float p0 = exp2f(ci[0]);
                const float p1 = exp2f(ci[1]);
                const float p2 = exp2f(ci[2]);
                const float p3 = exp2f(ci[3]);
                pw[t][0] = pk2bf(p0, p1);
                pw[t][1] = pk2bf(p2, p3);
            } else {
                pw[t][0] = 0u; pw[t][1] = 0u;
            }
        }

        // P -> LDS [query=col][key], XOR-swizzled 16B chunks (row = 128B = 8 chunks).
        unsigned short* psb = &Ps[wave][col * 64];
        #pragma unroll
        for (int t = 0; t < 4; ++t)
            *(uint2*)(psb + ((2 * t + (quad >> 1)) ^ sw) * 8 + (quad & 1) * 4) =
                make_uint2(pw[t][0], pw[t][1]);

        pa0p = *(const bf16x8*)(psb + (quad ^ sw) * 8);        // keys 0..31
        pa1p = *(const bf16x8*)(psb + ((4 + quad) ^ sw) * 8);  // keys 32..63

        // V frags of tile jt into registers (cross-wave Kbuf rows!)
        #pragma unroll
        for (int t = 0; t < 4; ++t) {
            const int row = (t * 16 + col) * 64;
            vlo[t] = *(const bf16x8*)&Ktc[row + (quad ^ sw) * 8];
            vhi[t] = *(const bf16x8*)&Ktc[row + ((4 + quad) ^ sw) * 8];
        }
        // RACE FIX: these ds_reads must complete before B1 of the next
        // iteration (other waves' DMAs overwrite buf[cur] right after B1).
        // Raw s_barrier does NOT drain lgkmcnt; force it here, and pin the
        // loads with a sched_barrier so they can't be sunk past it.
        __asm__ volatile("s_waitcnt lgkmcnt(0)" ::: "memory");
        __builtin_amdgcn_sched_barrier(0);
    }

    // flush: PV of the last (diagonal) tile; masked keys carry P=0, so both
    // halves are safe unconditionally.
    #pragma unroll
    for (int t = 0; t < 4; ++t) {
        accO[t] = __builtin_amdgcn_mfma_f32_16x16x32_bf16(pa0p, vlo[t], accO[t], 0, 0, 0);
        accO[t] = __builtin_amdgcn_mfma_f32_16x16x32_bf16(pa1p, vhi[t], accO[t], 0, 0, 0);
    }
    accL = __builtin_amdgcn_mfma_f32_16x16x32_bf16(pa0p, ones, accL, 0, 0, 0);
    accL = __builtin_amdgcn_mfma_f32_16x16x32_bf16(pa1p, ones, accL, 0, 0, 0);

    // epilogue: accL[r] = denominator for query quad*4+r (replicated over cols)
    #pragma unroll
    for (int r = 0; r < 4; ++r) {
        const float inv = 1.f / accL[r];
        const size_t row = (size_t)b * 2048 + qtile * 64 + wave * 16 + quad * 4 + r;
        unsigned short* op = aout + row * 1024 + h * 64;
        op[col]      = f2bf(accO[0][r] * inv);
        op[16 + col] = f2bf(accO[1][r] * inv);
        op[32 + col] = f2bf(accO[2][r] * inv);
        op[48 + col] = f2bf(accO[3][r] * inv);
    }
}

// ---------- launch ----------
extern "C" void kernel_launch(void* const* d_in, const int* in_sizes, int n_in,
                              void* d_out, int out_size, void* d_ws, size_t ws_size,
                              hipStream_t stream) {
    (void)in_sizes; (void)n_in; (void)out_size; (void)ws_size;
    const float* x    = (const float*)d_in[0];   // [2,2048,1024]
    const float* Wqk  = (const float*)d_in[1];   // [1024,2048]
    const float* Wout = (const float*)d_in[2];   // [1024,1024]
    float* out = (float*)d_out;                  // [2,2048,1024] fp32

    unsigned short* xb     = (unsigned short*)d_ws;            // [4096][1024]
    unsigned short* Wqk_t  = xb     + (size_t)4096 * 1024;     // [2048][1024]
    unsigned short* Wout_t = Wqk_t  + (size_t)2048 * 1024;     // [1024][1024]
    unsigned short* qkb    = Wout_t + (size_t)1024 * 1024;     // [4096][2048]
    unsigned short* aoutb  = qkb    + (size_t)4096 * 2048;     // [4096][1024]
    unsigned short* kT     = xb;                               // [2048][2048] (x dead after GEMM1)

    // fused prep: cast_x + Wqk^T + Wout^T in one dispatch
    prep_kernel<<<dim3(5120), dim3(256), 0, stream>>>(x, Wqk, Wout, xb, Wqk_t, Wout_t);

    // qk = x @ W_qk -> bf16 [4096][2048]   (64x128 tiles, BK=64: 1024 blocks = 4/CU)
    gemm64k_kernel<true><<<dim3(64, 16), dim3(256), 0, stream>>>(
        xb, Wqk_t, (void*)qkb, 1024, 1024, 1024, 2048);

    // K^T per batch: [b*1024+f][token]
    ktrans_kernel<<<dim3(32, 16, 2), dim3(256), 0, stream>>>(qkb, kT);

    // causal MFMA flash attention (deferred-PV, race-fixed) -> bf16 [4096][1024]
    attn_v16_kernel<<<dim3(32, 32), dim3(256), 0, stream>>>(qkb, kT, aoutb);

    // out = attn_out @ W_out -> fp32       (64x128 tiles, BK=64: 512 blocks = 2/CU)
    gemm64k_kernel<false><<<dim3(64, 8), dim3(256), 0, stream>>>(
        aoutb, Wout_t, (void*)out, 1024, 1024, 1024, 1024);
}

// Round 14
// 161.490 us; speedup vs baseline: 1.0926x; 1.0345x over previous
//
#include <hip/hip_runtime.h>
#include <hip/hip_bf16.h>
#include <math.h>

// ---------- helpers ----------
typedef short bf16x8 __attribute__((ext_vector_type(8)));
typedef float f32x4 __attribute__((ext_vector_type(4)));

__device__ __forceinline__ float bf2f(unsigned short u) {
    return __uint_as_float(((unsigned int)u) << 16);
}
__device__ __forceinline__ unsigned short f2bf(float f) {
    unsigned int u = __float_as_uint(f);
    u = (u + 0x7FFFu + ((u >> 16) & 1u)) >> 16;
    return (unsigned short)u;
}
__device__ __forceinline__ unsigned int pk2bf(float a, float b) {
    __hip_bfloat162 u = __float22bfloat162_rn(make_float2(a, b));
    return *(unsigned int*)&u;
}

// async global->LDS, 16B per lane; LDS dest = wave-uniform base + lane*16
#define ASYNC16(gp, lp)                                                        \
    __builtin_amdgcn_global_load_lds(                                          \
        (const __attribute__((address_space(1))) unsigned int*)(gp),           \
        (__attribute__((address_space(3))) unsigned int*)(lp), 16, 0, 0)

// ---------- fused prep: cast_x (blocks 0..2047), Wqk^T (2048..4095), Wout^T (4096..5119) ----------
__global__ __launch_bounds__(256) void prep_kernel(const float* __restrict__ x,
                                                   const float* __restrict__ Wqk,
                                                   const float* __restrict__ Wout,
                                                   unsigned short* __restrict__ xb,
                                                   unsigned short* __restrict__ Wqk_t,
                                                   unsigned short* __restrict__ Wout_t) {
    __shared__ float tile[32][33];
    const int bid = blockIdx.x;
    const int tid = threadIdx.x;

    if (bid < 2048) {
        // ---- cast x: fp32 -> bf16, 8 elems/thread ----
        const int i = (bid * 256 + tid) * 8;
        float4 a = *(const float4*)(x + i);
        float4 b = *(const float4*)(x + i + 4);
        bf16x8 v;
        v[0] = (short)f2bf(a.x); v[1] = (short)f2bf(a.y); v[2] = (short)f2bf(a.z); v[3] = (short)f2bf(a.w);
        v[4] = (short)f2bf(b.x); v[5] = (short)f2bf(b.y); v[6] = (short)f2bf(b.z); v[7] = (short)f2bf(b.w);
        *(bf16x8*)(xb + i) = v;
        return;
    }

    // ---- transpose+cast: fp32 [K][N] -> bf16 [N][K] ----
    const float* in;
    unsigned short* out;
    int K, N, t;
    if (bid < 4096) { t = bid - 2048; in = Wqk;  out = Wqk_t;  K = 1024; N = 2048; }
    else            { t = bid - 4096; in = Wout; out = Wout_t; K = 1024; N = 1024; }
    const int k0 = (t & 31) * 32, n0 = (t >> 5) * 32;
    const int tx = tid & 31, ty = tid >> 5;
    #pragma unroll
    for (int i = ty; i < 32; i += 8)
        tile[i][tx] = in[(size_t)(k0 + i) * N + (n0 + tx)];
    __syncthreads();
    #pragma unroll
    for (int i = ty; i < 32; i += 8)
        out[(size_t)(n0 + i) * K + (k0 + tx)] = f2bf(tile[tx][i]);
}

// ---------- prep: bf16 k-half of qkb [token][feature] -> kT [b*1024+f][token] ----------
// (fallback path only, when workspace is too small for a dedicated kT region)
__global__ __launch_bounds__(256) void ktrans_kernel(const unsigned short* __restrict__ qkb,
                                                     unsigned short* __restrict__ kT) {
    __shared__ unsigned short tl[64][68];
    const int b = blockIdx.z;
    const int tok0 = blockIdx.x * 64;
    const int f0 = blockIdx.y * 64;
    const int r = threadIdx.x >> 4;        // 0..15
    const int c = (threadIdx.x & 15) * 4;  // 0..60
    #pragma unroll
    for (int i = 0; i < 4; ++i) {
        const int rr = r + 16 * i;
        ushort4 v = *(const ushort4*)(qkb + ((size_t)(b * 2048 + tok0 + rr)) * 2048 + 1024 + f0 + c);
        *(ushort4*)&tl[rr][c] = v;
    }
    __syncthreads();
    #pragma unroll
    for (int i = 0; i < 4; ++i) {
        const int fr = r + 16 * i;
        ushort4 v;
        v.x = tl[c + 0][fr]; v.y = tl[c + 1][fr]; v.z = tl[c + 2][fr]; v.w = tl[c + 3][fr];
        *(ushort4*)(kT + ((size_t)(b * 1024 + f0 + fr)) * 2048 + tok0 + c) = v;
    }
}

// ---------- 64x128-tile, BK=64 MFMA GEMM (v13 body) + optional fused K-transpose ----------
// WRITE_KT: blocks with n0 >= 1024 (the k-half of qkb) additionally transpose
// their 64x128 output tile via LDS (reusing the staging buffers, pad 68 for
// 8B-aligned rows) and write kT [b*1024+f][token] coalesced (64B/thread,
// 128B per feature row). Values are f2bf(acc) - bit-identical to the
// standalone ktrans path. Removes one full dispatch + an 8MB qkb re-read.
template <bool STORE_BF16, bool WRITE_KT>
__global__ __launch_bounds__(256) void gemm64k_kernel(const unsigned short* __restrict__ A,
                                                      const unsigned short* __restrict__ Bt,
                                                      void* __restrict__ C,
                                                      unsigned short* __restrict__ kTout,
                                                      int K, int lda, int ldb, int ldc) {
    __shared__ unsigned short smem[64 * 64 + 128 * 64];  // As | Bs (24 KB)
    unsigned short* As = smem;                           // [64][64]
    unsigned short* Bs = smem + 64 * 64;                 // [128][64]
    const int tid = threadIdx.x;
    const int wave = tid >> 6;
    const int lane = tid & 63;
    const int quad = lane >> 4;
    const int col  = lane & 15;
    const int sw   = col & 7;                 // read-side XOR key
    const int wm = (wave >> 1) * 32;          // 2 waves over M (64)
    const int wn = (wave & 1) * 64;           // 2 waves over N (128)
    const int m0 = blockIdx.x * 64, n0 = blockIdx.y * 128;

    f32x4 acc[2][4];
    #pragma unroll
    for (int i = 0; i < 2; ++i)
        #pragma unroll
        for (int j = 0; j < 4; ++j) { acc[i][j][0] = 0.f; acc[i][j][1] = 0.f; acc[i][j][2] = 0.f; acc[i][j][3] = 0.f; }

    // staging: wave covers rows wave*8 + r8 (+32/+64/+96), chunk c8 = (lane&7)^r8
    const int r8 = lane >> 3;
    const int c8 = (lane & 7) ^ r8;

    for (int k0 = 0; k0 < K; k0 += 64) {
        __syncthreads();
        const unsigned short* ga = A  + (size_t)(m0 + wave * 8 + r8) * lda + k0 + c8 * 8;
        const unsigned short* gb = Bt + (size_t)(n0 + wave * 8 + r8) * ldb + k0 + c8 * 8;
        ASYNC16(ga,            &As[(wave * 8) * 64]);        // A rows 0..31
        ASYNC16(ga + 32 * lda, &As[(32 + wave * 8) * 64]);   // A rows 32..63
        ASYNC16(gb,            &Bs[(wave * 8) * 64]);        // B rows 0..31
        ASYNC16(gb + 32 * ldb, &Bs[(32 + wave * 8) * 64]);   // B rows 32..63
        ASYNC16(gb + 64 * ldb, &Bs[(64 + wave * 8) * 64]);   // B rows 64..95
        ASYNC16(gb + 96 * ldb, &Bs[(96 + wave * 8) * 64]);   // B rows 96..127
        __syncthreads();

        bf16x8 af[2][2], bf[4][2];
        #pragma unroll
        for (int mf = 0; mf < 2; ++mf) {
            const int base = (wm + mf * 16 + col) * 64;
            af[mf][0] = *(const bf16x8*)&As[base + ((quad    ) ^ sw) * 8];
            af[mf][1] = *(const bf16x8*)&As[base + ((quad + 4) ^ sw) * 8];
        }
        #pragma unroll
        for (int nf = 0; nf < 4; ++nf) {
            const int base = (wn + nf * 16 + col) * 64;
            bf[nf][0] = *(const bf16x8*)&Bs[base + ((quad    ) ^ sw) * 8];
            bf[nf][1] = *(const bf16x8*)&Bs[base + ((quad + 4) ^ sw) * 8];
        }
        #pragma unroll
        for (int mf = 0; mf < 2; ++mf)
            #pragma unroll
            for (int nf = 0; nf < 4; ++nf) {
                acc[mf][nf] = __builtin_amdgcn_mfma_f32_16x16x32_bf16(af[mf][0], bf[nf][0], acc[mf][nf], 0, 0, 0);
                acc[mf][nf] = __builtin_amdgcn_mfma_f32_16x16x32_bf16(af[mf][1], bf[nf][1], acc[mf][nf], 0, 0, 0);
            }
    }

    #pragma unroll
    for (int mf = 0; mf < 2; ++mf) {
        const int row0 = m0 + wm + mf * 16 + quad * 4;
        #pragma unroll
        for (int nf = 0; nf < 4; ++nf) {
            const int cc = n0 + wn + nf * 16 + col;
            #pragma unroll
            for (int r = 0; r < 4; ++r) {
                if (STORE_BF16)
                    ((unsigned short*)C)[(size_t)(row0 + r) * ldc + cc] = f2bf(acc[mf][nf][r]);
                else
                    ((float*)C)[(size_t)(row0 + r) * ldc + cc] = acc[mf][nf][r];
            }
        }
    }

    // ---- fused K-transpose epilogue (k-half blocks only; block-uniform branch) ----
    if (WRITE_KT && n0 >= 1024) {
        __syncthreads();  // all waves done reading As/Bs (last K-tile)
        // transposed store into LDS: tt[feat][tok], pad 68 (136B rows: 8B-aligned)
        unsigned short* tt = smem;  // 128*68 = 8704 shorts <= 12288 available
        #pragma unroll
        for (int mf = 0; mf < 2; ++mf)
            #pragma unroll
            for (int nf = 0; nf < 4; ++nf)
                #pragma unroll
                for (int r = 0; r < 4; ++r)
                    tt[(wn + nf * 16 + col) * 68 + (wm + mf * 16 + quad * 4 + r)] =
                        f2bf(acc[mf][nf][r]);
        __syncthreads();
        // coalesced write: thread covers feature f = tid/2, 32 tokens (half row)
        const int b = m0 >> 11, token0 = m0 & 2047, f0 = n0 - 1024;
        const int f = tid >> 1, half = tid & 1;
        unsigned short* kout =
            kTout + ((size_t)(b * 1024 + f0 + f)) * 2048 + token0 + half * 32;
        #pragma unroll
        for (int j = 0; j < 8; ++j)
            *(ushort4*)(kout + j * 4) = *(const ushort4*)&tt[f * 68 + half * 32 + j * 4];
    }
}

// ---------- MFMA flash attention v16: deferred-PV pipeline, race-fixed (frozen) ----------
__global__ __launch_bounds__(256, 4) void attn_v16_kernel(const unsigned short* __restrict__ qkb,
                                                          const unsigned short* __restrict__ kT,
                                                          unsigned short* __restrict__ aout) {
    __shared__ unsigned short Kbuf[2][2][64 * 64];  // [buf][Kn|Kt][key/dim][64], swizzled
    __shared__ unsigned short Ps[4][16 * 64];       // per-wave P: [query][key], XOR-swizzled

    const int bh = blockIdx.x;
    const int b = bh >> 4, h = bh & 15;
    const int qtile = 31 - (int)blockIdx.y;         // heavy tiles dispatch first
    const int tid = threadIdx.x;
    const int wave = tid >> 6, lane = tid & 63, quad = lane >> 4, col = lane & 15;
    const int sw = col & 7;                         // per-row XOR swizzle key

    // Q frags (B-operand of S^T mfma), fold beta*log2(e) so exp -> exp2
    bf16x8 qa0, qa1;
    {
        const unsigned short* qp =
            qkb + ((size_t)(b * 2048 + qtile * 64 + wave * 16 + col)) * 2048 + h * 64;
        bf16x8 r0 = *(const bf16x8*)(qp + quad * 8);
        bf16x8 r1 = *(const bf16x8*)(qp + 32 + quad * 8);
        const float sc = 0.125f * 1.44269504088896f;
        #pragma unroll
        for (int i = 0; i < 8; ++i) {
            qa0[i] = (short)f2bf(bf2f((unsigned short)r0[i]) * sc);
            qa1[i] = (short)f2bf(bf2f((unsigned short)r1[i]) * sc);
        }
    }

    bf16x8 ones;
    #pragma unroll
    for (int i = 0; i < 8; ++i) ones[i] = (short)0x3F80;  // bf16 1.0

    f32x4 accO[4];  // O[q=quad*4+r][d=t*16+col]
    #pragma unroll
    for (int t = 0; t < 4; ++t) { accO[t][0] = 0.f; accO[t][1] = 0.f; accO[t][2] = 0.f; accO[t][3] = 0.f; }
    f32x4 accL = {0.f, 0.f, 0.f, 0.f};  // row-sum of P (denominator), via ones-MFMA

    // carried fragments: P and V of the previous tile (deferred PV)
    bf16x8 pa0p = {}, pa1p = {};
    bf16x8 vlo[4] = {}, vhi[4] = {};

    // staging: lane covers row r8=lane/8 of an 8-row group, global chunk (lane%8)^r8
    const int r8 = lane >> 3;
    const int c8 = (lane & 7) ^ r8;
    const unsigned short* knp =
        qkb + ((size_t)(b * 2048 + wave * 16 + r8)) * 2048 + 1024 + h * 64 + c8 * 8;
    const unsigned short* ktp = kT + ((size_t)(bh * 64 + wave * 16 + r8)) * 2048 + c8 * 8;

    auto issue = [&](int jt, int p) {
        const unsigned short* kn = knp + (size_t)jt * 64 * 2048;
        const unsigned short* kt = ktp + jt * 64;
        unsigned short* knl = &Kbuf[p][0][(wave * 16) * 64];
        unsigned short* ktl = &Kbuf[p][1][(wave * 16) * 64];
        ASYNC16(kn,            knl);
        ASYNC16(kn + 8 * 2048, knl + 8 * 64);
        ASYNC16(kt,            ktl);
        ASYNC16(kt + 8 * 2048, ktl + 8 * 64);
    };

    issue(0, 0);  // prologue: tile 0 -> buf 0

    for (int jt = 0; jt <= qtile; ++jt) {
        const int cur = jt & 1;
        __builtin_amdgcn_s_barrier();            // B1: all waves done reading buf[cur^1]
        if (jt < qtile) issue(jt + 1, cur ^ 1);  // prefetch next tile (4 async, in flight)
        if (jt < qtile) __builtin_amdgcn_s_waitcnt(0xF74);  // vmcnt(4): own tile-jt landed
        else            __builtin_amdgcn_s_waitcnt(0xF70);  // vmcnt(0): last tile
        __builtin_amdgcn_s_barrier();            // B2: everyone's tile-jt landed
        __asm__ volatile("" ::: "memory");       // fence compiler reordering across B2

        const unsigned short* Knc = &Kbuf[cur][0][0];
        const unsigned short* Ktc = &Kbuf[cur][1][0];

        const bool diag = (jt == qtile);
        const int tmax = diag ? wave : 3;        // frag t = keys [t*16, t*16+15]

        // ---- QK MFMAs for tile jt, then deferred PV for tile jt-1 ----
        f32x4 c[4];
        __builtin_amdgcn_s_setprio(1);
        #pragma unroll
        for (int t = 0; t < 4; ++t) {
            if (t <= tmax) {
                const int row = (t * 16 + col) * 64;
                bf16x8 ka0 = *(const bf16x8*)&Knc[row + (quad ^ sw) * 8];
                bf16x8 ka1 = *(const bf16x8*)&Knc[row + ((4 + quad) ^ sw) * 8];
                f32x4 ci = {-16.f, -16.f, -16.f, -16.f};   // exp2 bias, free
                ci = __builtin_amdgcn_mfma_f32_16x16x32_bf16(ka0, qa0, ci, 0, 0, 0);
                ci = __builtin_amdgcn_mfma_f32_16x16x32_bf16(ka1, qa1, ci, 0, 0, 0);
                c[t] = ci;
            }
        }
        if (jt) {  // PV of tile jt-1 (always a full non-diag tile) on the MFMA pipe
            #pragma unroll
            for (int t = 0; t < 4; ++t) {
                accO[t] = __builtin_amdgcn_mfma_f32_16x16x32_bf16(pa0p, vlo[t], accO[t], 0, 0, 0);
                accO[t] = __builtin_amdgcn_mfma_f32_16x16x32_bf16(pa1p, vhi[t], accO[t], 0, 0, 0);
            }
            accL = __builtin_amdgcn_mfma_f32_16x16x32_bf16(pa0p, ones, accL, 0, 0, 0);
            accL = __builtin_amdgcn_mfma_f32_16x16x32_bf16(pa1p, ones, accL, 0, 0, 0);
        }
        __builtin_amdgcn_s_setprio(0);

        // ---- softmax (VALU) overlaps the PV MFMAs above ----
        unsigned int pw[4][2];
        #pragma unroll
        for (int t = 0; t < 4; ++t) {
            if (t <= tmax) {
                f32x4 ci = c[t];
                if (diag && t == wave) {
                    #pragma unroll
                    for (int r = 0; r < 4; ++r)
                        if (quad * 4 + r > col) ci[r] = -1e30f;   // exp2 -> 0
                }
                const float p0 = exp2f(ci[0]);
                const float p1 = exp2f(ci[1]);
                const float p2 = exp2f(ci[2]);
                const float p3 = exp2f(ci[3]);
                pw[t][0] = pk2bf(p0, p1);
                pw[t][1] = pk2bf(p2, p3);
            } else {
                pw[t][0] = 0u; pw[t][1] = 0u;
            }
        }

        // P -> LDS [query=col][key], XOR-swizzled 16B chunks (row = 128B = 8 chunks).
        unsigned short* psb = &Ps[wave][col * 64];
        #pragma unroll
        for (int t = 0; t < 4; ++t)
            *(uint2*)(psb + ((2 * t + (quad >> 1)) ^ sw) * 8 + (quad & 1) * 4) =
                make_uint2(pw[t][0], pw[t][1]);

        pa0p = *(const bf16x8*)(psb + (quad ^ sw) * 8);        // keys 0..31
        pa1p = *(const bf16x8*)(psb + ((4 + quad) ^ sw) * 8);  // keys 32..63

        // V frags of tile jt into registers (cross-wave Kbuf rows!)
        #pragma unroll
        for (int t = 0; t < 4; ++t) {
            const int row = (t * 16 + col) * 64;
            vlo[t] = *(const bf16x8*)&Ktc[row + (quad ^ sw) * 8];
            vhi[t] = *(const bf16x8*)&Ktc[row + ((4 + quad) ^ sw) * 8];
        }
        // RACE FIX: these ds_reads must complete before B1 of the next
        // iteration (other waves' DMAs overwrite buf[cur] right after B1).
        // Raw s_barrier does NOT drain lgkmcnt; force it here, and pin the
        // loads with a sched_barrier so they can't be sunk past it.
        __asm__ volatile("s_waitcnt lgkmcnt(0)" ::: "memory");
        __builtin_amdgcn_sched_barrier(0);
    }

    // flush: PV of the last (diagonal) tile; masked keys carry P=0, so both
    // halves are safe unconditionally.
    #pragma unroll
    for (int t = 0; t < 4; ++t) {
        accO[t] = __builtin_amdgcn_mfma_f32_16x16x32_bf16(pa0p, vlo[t], accO[t], 0, 0, 0);
        accO[t] = __builtin_amdgcn_mfma_f32_16x16x32_bf16(pa1p, vhi[t], accO[t], 0, 0, 0);
    }
    accL = __builtin_amdgcn_mfma_f32_16x16x32_bf16(pa0p, ones, accL, 0, 0, 0);
    accL = __builtin_amdgcn_mfma_f32_16x16x32_bf16(pa1p, ones, accL, 0, 0, 0);

    // epilogue: accL[r] = denominator for query quad*4+r (replicated over cols)
    #pragma unroll
    for (int r = 0; r < 4; ++r) {
        const float inv = 1.f / accL[r];
        const size_t row = (size_t)b * 2048 + qtile * 64 + wave * 16 + quad * 4 + r;
        unsigned short* op = aout + row * 1024 + h * 64;
        op[col]      = f2bf(accO[0][r] * inv);
        op[16 + col] = f2bf(accO[1][r] * inv);
        op[32 + col] = f2bf(accO[2][r] * inv);
        op[48 + col] = f2bf(accO[3][r] * inv);
    }
}

// ---------- launch ----------
extern "C" void kernel_launch(void* const* d_in, const int* in_sizes, int n_in,
                              void* d_out, int out_size, void* d_ws, size_t ws_size,
                              hipStream_t stream) {
    (void)in_sizes; (void)n_in; (void)out_size;
    const float* x    = (const float*)d_in[0];   // [2,2048,1024]
    const float* Wqk  = (const float*)d_in[1];   // [1024,2048]
    const float* Wout = (const float*)d_in[2];   // [1024,1024]
    float* out = (float*)d_out;                  // [2,2048,1024] fp32

    unsigned short* xb     = (unsigned short*)d_ws;            // [4096][1024]  8 MB
    unsigned short* Wqk_t  = xb     + (size_t)4096 * 1024;     // [2048][1024]  4 MB
    unsigned short* Wout_t = Wqk_t  + (size_t)2048 * 1024;     // [1024][1024]  2 MB
    unsigned short* qkb    = Wout_t + (size_t)1024 * 1024;     // [4096][2048] 16 MB
    unsigned short* aoutb  = qkb    + (size_t)4096 * 2048;     // [4096][1024]  8 MB
    unsigned short* kT_new = aoutb  + (size_t)4096 * 1024;     // [2048][2048]  8 MB (46 MB total)

    const bool fused_kt = ws_size >= (size_t)46 * 1024 * 1024;
    unsigned short* kT = fused_kt ? kT_new : xb;  // fallback: alias xb (x dead after GEMM1)

    // fused prep: cast_x + Wqk^T + Wout^T in one dispatch
    prep_kernel<<<dim3(5120), dim3(256), 0, stream>>>(x, Wqk, Wout, xb, Wqk_t, Wout_t);

    if (fused_kt) {
        // qk = x @ W_qk -> bf16 [4096][2048]; k-half blocks also write kT
        gemm64k_kernel<true, true><<<dim3(64, 16), dim3(256), 0, stream>>>(
            xb, Wqk_t, (void*)qkb, kT, 1024, 1024, 1024, 2048);
    } else {
        gemm64k_kernel<true, false><<<dim3(64, 16), dim3(256), 0, stream>>>(
            xb, Wqk_t, (void*)qkb, nullptr, 1024, 1024, 1024, 2048);
        // K^T per batch: [b*1024+f][token]
        ktrans_kernel<<<dim3(32, 16, 2), dim3(256), 0, stream>>>(qkb, kT);
    }

    // causal MFMA flash attention (deferred-PV, race-fixed) -> bf16 [4096][1024]
    attn_v16_kernel<<<dim3(32, 32), dim3(256), 0, stream>>>(qkb, kT, aoutb);

    // out = attn_out @ W_out -> fp32
    gemm64k_kernel<false, false><<<dim3(64, 8), dim3(256), 0, stream>>>(
        aoutb, Wout_t, (void*)out, nullptr, 1024, 1024, 1024, 1024);
}